// Round 3
// baseline (331.973 us; speedup 1.0000x reference)
//
#include <hip/hip_runtime.h>

#define LOG2E 1.44269504088896340736f
#define LN2   0.69314718055994530942f

static constexpr int NT     = 32;          // num tags
static constexpr int SEQ    = 16384;
static constexpr int LC     = 32;          // steps per phase-1 chunk (1 wave/chunk)
static constexpr int CHUNKS = SEQ / LC;    // 512
static constexpr int GROUP  = 16;          // chunks folded per phase-2a wave
static constexpr int NB2    = CHUNKS / GROUP; // 32
// START = 0, END = 1 (masking already applied to `transitions` on host)

typedef __attribute__((ext_vector_type(8)))  short short8;     // 8 bf16 (4 VGPRs)
typedef __attribute__((ext_vector_type(16))) float float16_t;  // MFMA 32x32 acc

union U8 { unsigned u[4]; short8 s; };

// round-half-up fp32 -> bf16, pack two into one u32 (lo = a, hi = b)
__device__ __forceinline__ unsigned pack_bf16(float a, float b) {
    unsigned ua = (__float_as_uint(a) + 0x8000u) >> 16;
    unsigned ub = (__float_as_uint(b) + 0x8000u) & 0xFFFF0000u;
    return ua | ub;
}

__device__ __forceinline__ float wave_max(float v) {
    #pragma unroll
    for (int m = 1; m <= 32; m <<= 1) v = fmaxf(v, __shfl_xor(v, m, 64));
    return v;
}

// C-layout (lane holds col c, rows 4h+(reg&3)+8(reg>>2)) -> B-fragment
// (lane holds col c, k = 8h+j packed order). Half-lane exchange, verified R2.
#define PACK_SWAP_TO_B(ACC, B0, B1)                                          \
    {                                                                        \
        unsigned P0 = pack_bf16(ACC[0],  ACC[1]);                            \
        unsigned P1 = pack_bf16(ACC[2],  ACC[3]);                            \
        unsigned P2 = pack_bf16(ACC[4],  ACC[5]);                            \
        unsigned P3 = pack_bf16(ACC[6],  ACC[7]);                            \
        unsigned P4 = pack_bf16(ACC[8],  ACC[9]);                            \
        unsigned P5 = pack_bf16(ACC[10], ACC[11]);                           \
        unsigned P6 = pack_bf16(ACC[12], ACC[13]);                           \
        unsigned P7 = pack_bf16(ACC[14], ACC[15]);                           \
        unsigned q0 = __shfl_xor(P0, 32, 64), q1 = __shfl_xor(P1, 32, 64);   \
        unsigned q2 = __shfl_xor(P2, 32, 64), q3 = __shfl_xor(P3, 32, 64);   \
        unsigned q4 = __shfl_xor(P4, 32, 64), q5 = __shfl_xor(P5, 32, 64);   \
        unsigned q6 = __shfl_xor(P6, 32, 64), q7 = __shfl_xor(P7, 32, 64);   \
        B0.u[0] = hi ? q2 : P0; B0.u[1] = hi ? q3 : P1;                      \
        B0.u[2] = hi ? P2 : q0; B0.u[3] = hi ? P3 : q1;                      \
        B1.u[0] = hi ? q6 : P4; B1.u[1] = hi ? q7 : P5;                      \
        B1.u[2] = hi ? P6 : q4; B1.u[3] = hi ? P7 : q5;                      \
    }

#define IDENTITY_B(B0, B1)                                                   \
    {                                                                        \
        _Pragma("unroll")                                                    \
        for (int q = 0; q < 4; ++q) {                                        \
            unsigned lo = ((8*h + 2*q)     == c) ? 0x3F80u : 0u;             \
            unsigned hb = ((8*h + 2*q + 1) == c) ? 0x3F80u : 0u;             \
            B0.u[q] = lo | (hb << 16);                                       \
            lo = ((16 + 8*h + 2*q)     == c) ? 0x3F80u : 0u;                 \
            hb = ((16 + 8*h + 2*q + 1) == c) ? 0x3F80u : 0u;                 \
            B1.u[q] = lo | (hb << 16);                                       \
        }                                                                    \
    }

#define MATRIX_RESCALE(ACC, SINT)                                            \
    {                                                                        \
        float mx = ACC[0];                                                   \
        _Pragma("unroll")                                                    \
        for (int i = 1; i < 16; ++i) mx = fmaxf(mx, ACC[i]);                 \
        mx = wave_max(mx);                                                   \
        if (mx >= 1.1754944e-38f) {                                          \
            int ex = (int)((__float_as_uint(mx) >> 23) & 255) - 127;         \
            _Pragma("unroll")                                                \
            for (int i = 0; i < 16; ++i) ACC[i] = ldexpf(ACC[i], -ex);       \
            SINT += ex;                                                      \
        }                                                                    \
    }

// ---------------------------------------------------------------------------
// Phase 1: one wave per 32-step chunk. Q <- diag(E_t) * W^T * Q  in bf16 MFMA
// frags (A = W^T constant, 2 MFMAs/step), power-of-2 matrix rescale every 4
// steps. Output: mantissa-normalized bf16 matrix (row-major u16, max in
// [1,2)) consumable directly as phase-2a A-fragments + fp32 log2-scale.
// ---------------------------------------------------------------------------
__global__ __launch_bounds__(64, 1)
void crf_phase1(const int* __restrict__ x, const float* __restrict__ emit,
                const float* __restrict__ trans,
                unsigned short* __restrict__ out1b, float* __restrict__ out1S)
{
    __shared__ __align__(16) float E[LC * NT];
    const int L = threadIdx.x;
    const int c = L & 31;
    const int h = L >> 5;
    const bool hi = (h != 0);
    const int chunk = blockIdx.x;

    // ---- stage exp2(emit * log2e) for this chunk into LDS ----
    int xv = x[chunk * LC + c];
    float ev[16];
    #pragma unroll
    for (int rr = 0; rr < 16; ++rr) {
        int t = 2 * rr + h;
        int xt = __shfl(xv, t, 64);
        ev[rr] = emit[(size_t)xt * NT + c];
    }
    #pragma unroll
    for (int rr = 0; rr < 16; ++rr)
        E[(2 * rr + h) * NT + c] = exp2f(ev[rr] * LOG2E);
    __syncthreads();

    // ---- constant A-fragment: W^T, A[m=c][k] = exp2(trans[k*32+c]*log2e) ----
    U8 A0, A1;
    #pragma unroll
    for (int q = 0; q < 4; ++q) {
        float w0 = exp2f(trans[(8*h + 2*q    ) * NT + c] * LOG2E);
        float w1 = exp2f(trans[(8*h + 2*q + 1) * NT + c] * LOG2E);
        A0.u[q] = pack_bf16(w0, w1);
        float w2 = exp2f(trans[(16 + 8*h + 2*q    ) * NT + c] * LOG2E);
        float w3 = exp2f(trans[(16 + 8*h + 2*q + 1) * NT + c] * LOG2E);
        A1.u[q] = pack_bf16(w2, w3);
    }

    U8 B0, B1;
    IDENTITY_B(B0, B1);

    int sInt = 0;
    float16_t acc;
    for (int t = 0; t < LC; ++t) {
        float16_t z = {};
        acc = __builtin_amdgcn_mfma_f32_32x32x16_bf16(A0.s, B0.s, z,   0, 0, 0);
        acc = __builtin_amdgcn_mfma_f32_32x32x16_bf16(A1.s, B1.s, acc, 0, 0, 0);

        // row scale by E_t: row r = 4h + (reg&3) + 8*(reg>>2)
        const float* Et = &E[t * NT + 4 * h];
        float4 e0 = *(const float4*)(Et);
        float4 e1 = *(const float4*)(Et + 8);
        float4 e2 = *(const float4*)(Et + 16);
        float4 e3 = *(const float4*)(Et + 24);
        acc[0]  *= e0.x; acc[1]  *= e0.y; acc[2]  *= e0.z; acc[3]  *= e0.w;
        acc[4]  *= e1.x; acc[5]  *= e1.y; acc[6]  *= e1.z; acc[7]  *= e1.w;
        acc[8]  *= e2.x; acc[9]  *= e2.y; acc[10] *= e2.z; acc[11] *= e2.w;
        acc[12] *= e3.x; acc[13] *= e3.y; acc[14] *= e3.z; acc[15] *= e3.w;

        if ((t & 3) == 3) MATRIX_RESCALE(acc, sInt);   // incl. final t=31
        if (t + 1 < LC) PACK_SWAP_TO_B(acc, B0, B1);
    }

    // ---- bf16 store, row-major (phase2a A-fragment order) ----
    unsigned short* o = out1b + (size_t)chunk * (NT * NT);
    #pragma unroll
    for (int i = 0; i < 16; ++i) {
        int r = 4 * h + (i & 3) + 8 * (i >> 2);
        o[r * NT + c] = (unsigned short)((__float_as_uint(acc[i]) + 0x8000u) >> 16);
    }
    if (L == 0) out1S[chunk] = (float)sInt;
}

// ---------------------------------------------------------------------------
// Phase 2a: one wave per 16-chunk group. X <- Q_n * X via MFMA with A loaded
// DIRECTLY from phase1's bf16 matrices (no exp2/log2 round-trip); rescale
// every fold; out2 = log2(X) + accumulated scales (fp32, log2 domain).
// ---------------------------------------------------------------------------
__global__ __launch_bounds__(64, 1)
void crf_phase2a(const unsigned short* __restrict__ out1b,
                 const float* __restrict__ out1S, float* __restrict__ out2)
{
    const int L = threadIdx.x;
    const int c = L & 31;
    const int h = L >> 5;
    const bool hi = (h != 0);
    const int w = blockIdx.x;

    U8 B0, B1;
    IDENTITY_B(B0, B1);

    float SC = 0.f;
    #pragma unroll
    for (int n = 0; n < GROUP; ++n) SC += out1S[w * GROUP + n];

    // A[m=c][k]: k = 8h.. (A0), 16+8h.. (A1); u16 row-major -> dwordx4 loads
    const unsigned* src = (const unsigned*)(out1b + (size_t)(w * GROUP) * (NT * NT));
    uint4 a0 = *(const uint4*)(src + c * 16 + 4 * h);
    uint4 a1 = *(const uint4*)(src + c * 16 + 8 + 4 * h);

    int sInt = 0;
    float16_t acc;
    for (int n = 0; n < GROUP; ++n) {
        U8 A0, A1;
        A0.u[0] = a0.x; A0.u[1] = a0.y; A0.u[2] = a0.z; A0.u[3] = a0.w;
        A1.u[0] = a1.x; A1.u[1] = a1.y; A1.u[2] = a1.z; A1.u[3] = a1.w;

        if (n + 1 < GROUP) {           // depth-1 prefetch
            const unsigned* s2 = (const unsigned*)
                (out1b + (size_t)(w * GROUP + n + 1) * (NT * NT));
            a0 = *(const uint4*)(s2 + c * 16 + 4 * h);
            a1 = *(const uint4*)(s2 + c * 16 + 8 + 4 * h);
        }

        float16_t z = {};
        acc = __builtin_amdgcn_mfma_f32_32x32x16_bf16(A0.s, B0.s, z,   0, 0, 0);
        acc = __builtin_amdgcn_mfma_f32_32x32x16_bf16(A1.s, B1.s, acc, 0, 0, 0);

        MATRIX_RESCALE(acc, sInt);
        if (n + 1 < GROUP) PACK_SWAP_TO_B(acc, B0, B1);
    }

    float* o = out2 + (size_t)w * (NT * NT);
    float addc = (float)sInt + SC;
    #pragma unroll
    for (int i = 0; i < 16; ++i) {
        int r = 4 * h + (i & 3) + 8 * (i >> 2);
        o[r * NT + c] = log2f(acc[i]) + addc;   // log2(0) = -inf ok
    }
}

// ---------------------------------------------------------------------------
// Phase 2b: single wave, barrier-free. alpha in a register (lane r holds
// al[r]), broadcast via shuffles; scan 32 folded matrices (log2 domain),
// final lse with T[:,END], convert to natural log.
// ---------------------------------------------------------------------------
__global__ __launch_bounds__(64, 1)
void crf_phase2b(const float* __restrict__ out2, const float* __restrict__ trans,
                 float* __restrict__ out)
{
    const int L = threadIdx.x;
    const int r = L & 31;
    const int h = L >> 5;

    float alr = (r == 0) ? 0.f : -10000.f * LOG2E;

    const float* src = out2 + r * NT + 16 * h;
    float4 v0 = *(const float4*)(src);
    float4 v1 = *(const float4*)(src + 4);
    float4 v2 = *(const float4*)(src + 8);
    float4 v3 = *(const float4*)(src + 12);

    for (int n = 0; n < NB2; ++n) {
        float vals[16] = {v0.x, v0.y, v0.z, v0.w, v1.x, v1.y, v1.z, v1.w,
                          v2.x, v2.y, v2.z, v2.w, v3.x, v3.y, v3.z, v3.w};
        if (n + 1 < NB2) {             // depth-1 prefetch
            const float* s2 = out2 + (size_t)(n + 1) * (NT * NT) + r * NT + 16 * h;
            v0 = *(const float4*)(s2);
            v1 = *(const float4*)(s2 + 4);
            v2 = *(const float4*)(s2 + 8);
            v3 = *(const float4*)(s2 + 12);
        }
        float mv = -3.0e38f;
        #pragma unroll
        for (int j = 0; j < 16; ++j) {
            float aj = __shfl(alr, 16 * h + j, 64);   // al[16h+j] from lane reg
            vals[j] = fmaxf(vals[j], -1e30f) + fmaxf(aj, -1e30f);
            mv = fmaxf(mv, vals[j]);
        }
        mv = fmaxf(mv, __shfl_xor(mv, 32, 64));
        float s = 0.f;
        #pragma unroll
        for (int j = 0; j < 16; ++j) s += exp2f(vals[j] - mv);
        s += __shfl_xor(s, 32, 64);
        alr = mv + log2f(s);           // valid in all lanes (both halves reduced)
    }

    // z = ln2 * lse2_j( al[j] + T[j,END]*log2e ),  END = 1
    float v = fmaxf(alr, -1e30f) + trans[r * NT + 1] * LOG2E;
    float mv = v;
    #pragma unroll
    for (int m = 1; m <= 16; m <<= 1) mv = fmaxf(mv, __shfl_xor(mv, m, 64));
    float s = exp2f(v - mv);
    #pragma unroll
    for (int m = 1; m <= 16; m <<= 1) s += __shfl_xor(s, m, 64);
    if (L == 0) out[0] = (mv + log2f(s)) * LN2;
}

extern "C" void kernel_launch(void* const* d_in, const int* in_sizes, int n_in,
                              void* d_out, int out_size, void* d_ws, size_t ws_size,
                              hipStream_t stream) {
    const int*   x     = (const int*)d_in[0];
    const float* emit  = (const float*)d_in[1];
    const float* trans = (const float*)d_in[2];
    float* out = (float*)d_out;

    char* ws = (char*)d_ws;
    unsigned short* ws1b = (unsigned short*)ws;              // 512 bf16 mats, 1 MB
    float* ws1S = (float*)(ws + (size_t)CHUNKS * NT * NT * 2);  // 512 scalars
    float* ws2  = ws1S + CHUNKS;                             // 32 fp32 log mats

    crf_phase1 <<<CHUNKS, 64, 0, stream>>>(x, emit, trans, ws1b, ws1S);
    crf_phase2a<<<NB2,    64, 0, stream>>>(ws1b, ws1S, ws2);
    crf_phase2b<<<1,      64, 0, stream>>>(ws2, trans, out);
}